// Round 1
// baseline (292.604 us; speedup 1.0000x reference)
//
#include <hip/hip_runtime.h>
#include <stdint.h>

#define MDIM 8192
#define NDIM 1536
#define KDIM 3072

#define BM 128
#define BN 128
#define BK 96            // three 32-k planes, each in the R2/R4-proven 64B-row swizzled layout

#define NMB ((KDIM / 64) * (NDIM / 64))

typedef unsigned short u16;
typedef float  f32x4  __attribute__((ext_vector_type(4)));
typedef __bf16 bf16x8 __attribute__((ext_vector_type(8)));

__device__ __forceinline__ u16 f2bf(float f) {
    union { float f; unsigned int u; } v; v.f = f;
    unsigned int u = v.u;
    return (u16)((u + 0x7fffu + ((u >> 16) & 1u)) >> 16);  // RNE
}

// ---------------- prep: build Bt = (mask .* w^T) in bf16, [N][K] ----------------
__global__ void prep_kernel(const float* __restrict__ w, const float* __restrict__ mask,
                            u16* __restrict__ Bt) {
    const int t = threadIdx.x;
    __shared__ float sw[64][65];
    const int kb = blockIdx.x % (KDIM / 64);
    const int nb = blockIdx.x / (KDIM / 64);
    const int k0 = kb * 64, n0 = nb * 64;
    {
        const int c4 = t & 15;
        const int r  = t >> 4;
#pragma unroll
        for (int rr = 0; rr < 4; ++rr) {
            int row = rr * 16 + r;
            float4 v = *(const float4*)&w[(size_t)(k0 + row) * NDIM + n0 + c4 * 4];
            sw[row][c4 * 4 + 0] = v.x;
            sw[row][c4 * 4 + 1] = v.y;
            sw[row][c4 * 4 + 2] = v.z;
            sw[row][c4 * 4 + 3] = v.w;
        }
    }
    __syncthreads();
    {
        const int n  = t >> 2;
        const int ks = (t & 3) * 16;
#pragma unroll
        for (int j = 0; j < 4; ++j) {
            int k = ks + j * 4;
            float4 mv = *(const float4*)&mask[(size_t)(n0 + n) * KDIM + k0 + k];
            ushort4 o;
            o.x = f2bf(mv.x * sw[k + 0][n]);
            o.y = f2bf(mv.y * sw[k + 1][n]);
            o.z = f2bf(mv.z * sw[k + 2][n]);
            o.w = f2bf(mv.w * sw[k + 3][n]);
            *(ushort4*)&Bt[(size_t)(n0 + n) * KDIM + k0 + k] = o;
        }
    }
}

// ---------------- fused GEMM: C = f32(x) @ Bt^T + bias, A cvt'd in-register ----------------
__device__ __forceinline__ void gload_lds16(const void* g, void* l) {
    __builtin_amdgcn_global_load_lds(
        (const __attribute__((address_space(1))) unsigned int*)g,
        (__attribute__((address_space(3))) unsigned int*)l, 16, 0, 0);
}

#define PLANE 4096   // u16 per k-plane (128 rows * 32)

__global__ void __launch_bounds__(256, 3)
gemm_kernel(const float* __restrict__ X,   // [M][K] fp32 (converted to bf16 in-register)
            const u16* __restrict__ B,     // [N][K] bf16
            const float* __restrict__ bias,
            float* __restrict__ C) {       // [M][N] fp32
    __shared__ u16 sA[3 * PLANE];  // 24 KiB
    __shared__ u16 sB[3 * PLANE];  // 24 KiB

    const int tid  = threadIdx.x;
    const int wave = tid >> 6;
    const int lane = tid & 63;

    // XCD-affine remap: bik = bx*64 + l*8 + xcd  ->  by = xcd*8 + l, bx = bik>>6
    const int bik = blockIdx.x;
    const int by  = (bik & 7) * 8 + ((bik >> 3) & 7);
    const int bx  = bik >> 6;
    const int m0 = by * BM, n0 = bx * BN;

    const int srow = lane >> 2;                       // row-within-16
    const int gc   = (lane & 3) ^ ((lane >> 3) & 3);  // swizzled global 16B/32B-chunk index

    // B staging (unchanged): global_load_lds, swizzle applied on global source
    const u16* gB0 = B + (size_t)(n0 + wave * 16 + srow) * KDIM + gc * 8;
    u16* lB0 = &sB[(wave * 16) * 32];
    u16* lB1 = &sB[(wave * 16 + 64) * 32];

    // A reg-staging: f32 load -> cvt_pk bf16 -> ds_write_b128, identical LDS layout
    //   (LDS slot 4r+c <- global chunk c^((r>>1)&3); per-wave write addr = lane*16, linear)
    const float* gXlo = X + (size_t)(m0 + wave * 16 + srow) * KDIM + gc * 8;
    const float* gXhi = gXlo + (size_t)64 * KDIM;
    u16* lA = &sA[(wave * 16 + srow) * 32 + (lane & 3) * 8];

    const int wm = (wave >> 1) * 64;
    const int wn = (wave & 1) * 64;
    const int fr = lane & 15;
    const int fq = lane >> 4;
    const int fsw = (fq ^ ((fr >> 1) & 3)) * 8;

    f32x4 acc[4][4] = {};
    f32x4 pa[12];   // prefetched A f32 for the CURRENT tile (statically indexed only)

    // prologue: A loads for k0 = 0
#pragma unroll
    for (int p = 0; p < 3; ++p) {
        pa[4 * p + 0] = *(const f32x4*)(gXlo + p * 32);
        pa[4 * p + 1] = *(const f32x4*)(gXlo + p * 32 + 4);
        pa[4 * p + 2] = *(const f32x4*)(gXhi + p * 32);
        pa[4 * p + 3] = *(const f32x4*)(gXhi + p * 32 + 4);
    }

    for (int k0 = 0; k0 < KDIM; k0 += BK) {
        __syncthreads();   // prev compute done (LDS reusable); drains our in-flight A loads
        // B: async global->LDS
#pragma unroll
        for (int p = 0; p < 3; ++p) {
            gload_lds16(gB0 + k0 + p * 32,                      lB0 + p * PLANE);
            gload_lds16(gB0 + k0 + p * 32 + (size_t)64 * KDIM,  lB1 + p * PLANE);
        }
        // A: cvt prefetched f32 -> bf16, write to LDS (overlaps B's global latency)
#pragma unroll
        for (int p = 0; p < 3; ++p) {
            bf16x8 lo, hi;
#pragma unroll
            for (int i = 0; i < 4; ++i) {
                lo[i]     = (__bf16)pa[4 * p + 0][i];
                lo[i + 4] = (__bf16)pa[4 * p + 1][i];
                hi[i]     = (__bf16)pa[4 * p + 2][i];
                hi[i + 4] = (__bf16)pa[4 * p + 3][i];
            }
            *(bf16x8*)(lA + p * PLANE)           = lo;
            *(bf16x8*)(lA + p * PLANE + 64 * 32) = hi;
        }
        __syncthreads();   // B gloads + A ds_writes visible

        // issue NEXT tile's A loads now: latency hides under the 48-MFMA compute phase,
        // drained only at the next iteration's first barrier
        const int kn = k0 + BK;
        if (kn < KDIM) {
#pragma unroll
            for (int p = 0; p < 3; ++p) {
                pa[4 * p + 0] = *(const f32x4*)(gXlo + kn + p * 32);
                pa[4 * p + 1] = *(const f32x4*)(gXlo + kn + p * 32 + 4);
                pa[4 * p + 2] = *(const f32x4*)(gXhi + kn + p * 32);
                pa[4 * p + 3] = *(const f32x4*)(gXhi + kn + p * 32 + 4);
            }
        }

#pragma unroll
        for (int h = 0; h < 3; ++h) {
            const u16* pA = &sA[h * PLANE];
            const u16* pB = &sB[h * PLANE];
            bf16x8 af[4], bfv[4];
#pragma unroll
            for (int mt = 0; mt < 4; ++mt)
                af[mt] = *(const bf16x8*)&pA[(wm + mt * 16 + fr) * 32 + fsw];
#pragma unroll
            for (int nt = 0; nt < 4; ++nt)
                bfv[nt] = *(const bf16x8*)&pB[(wn + nt * 16 + fr) * 32 + fsw];
#pragma unroll
            for (int mt = 0; mt < 4; ++mt)
#pragma unroll
                for (int nt = 0; nt < 4; ++nt)
                    acc[mt][nt] = __builtin_amdgcn_mfma_f32_16x16x32_bf16(
                        af[mt], bfv[nt], acc[mt][nt], 0, 0, 0);
        }
    }

    // epilogue: C/D layout col = lane&15, row = (lane>>4)*4 + reg  [m89-verified]
#pragma unroll
    for (int nt = 0; nt < 4; ++nt) {
        int n = n0 + wn + nt * 16 + fr;
        float bv = bias[n];
#pragma unroll
        for (int mt = 0; mt < 4; ++mt) {
            int m = m0 + wm + mt * 16 + fq * 4;
#pragma unroll
            for (int r = 0; r < 4; ++r)
                C[(size_t)(m + r) * NDIM + n] = acc[mt][nt][r] + bv;
        }
    }
}

extern "C" void kernel_launch(void* const* d_in, const int* in_sizes, int n_in,
                              void* d_out, int out_size, void* d_ws, size_t ws_size,
                              hipStream_t stream) {
    const float* x    = (const float*)d_in[0];   // [8192][3072] fp32
    const float* w    = (const float*)d_in[1];   // [3072][1536] fp32
    const float* bias = (const float*)d_in[2];   // [1536]
    const float* mask = (const float*)d_in[3];   // [1536][3072] fp32
    float* out = (float*)d_out;                  // [8192][1536] fp32

    u16* Bt = (u16*)d_ws;                        // 9437184 B

    prep_kernel<<<NMB, 256, 0, stream>>>(w, mask, Bt);
    gemm_kernel<<<(MDIM / BM) * (NDIM / BN), 256, 0, stream>>>(x, Bt, bias, out);
}

// Round 2
// 261.121 us; speedup vs baseline: 1.1206x; 1.1206x over previous
//
#include <hip/hip_runtime.h>
#include <stdint.h>

#define MDIM 8192
#define NDIM 1536
#define KDIM 3072

#define BM 128
#define BN 128
#define BK 96            // three 32-k planes, each in the R2/R4-proven 64B-row swizzled layout

#define NMB ((KDIM / 64) * (NDIM / 64))
#define NCVT ((MDIM * KDIM / 4) / 256)

typedef unsigned short u16;
typedef float  f32x4  __attribute__((ext_vector_type(4)));
typedef __bf16 bf16x8 __attribute__((ext_vector_type(8)));

__device__ __forceinline__ u16 f2bf(float f) {
    union { float f; unsigned int u; } v; v.f = f;
    unsigned int u = v.u;
    return (u16)((u + 0x7fffu + ((u >> 16) & 1u)) >> 16);  // RNE
}

// ---------------- fused prep: make_b blocks, then cvt_x blocks ----------------
__global__ void prep_kernel(const float* __restrict__ w, const float* __restrict__ mask,
                            u16* __restrict__ Bt,
                            const float4* __restrict__ x, ushort4* __restrict__ xb) {
    const int t = threadIdx.x;
    if (blockIdx.x < NMB) {
        __shared__ float sw[64][65];
        const int kb = blockIdx.x % (KDIM / 64);
        const int nb = blockIdx.x / (KDIM / 64);
        const int k0 = kb * 64, n0 = nb * 64;
        {
            const int c4 = t & 15;
            const int r  = t >> 4;
#pragma unroll
            for (int rr = 0; rr < 4; ++rr) {
                int row = rr * 16 + r;
                float4 v = *(const float4*)&w[(size_t)(k0 + row) * NDIM + n0 + c4 * 4];
                sw[row][c4 * 4 + 0] = v.x;
                sw[row][c4 * 4 + 1] = v.y;
                sw[row][c4 * 4 + 2] = v.z;
                sw[row][c4 * 4 + 3] = v.w;
            }
        }
        __syncthreads();
        {
            const int n  = t >> 2;
            const int ks = (t & 3) * 16;
#pragma unroll
            for (int j = 0; j < 4; ++j) {
                int k = ks + j * 4;
                float4 mv = *(const float4*)&mask[(size_t)(n0 + n) * KDIM + k0 + k];
                ushort4 o;
                o.x = f2bf(mv.x * sw[k + 0][n]);
                o.y = f2bf(mv.y * sw[k + 1][n]);
                o.z = f2bf(mv.z * sw[k + 2][n]);
                o.w = f2bf(mv.w * sw[k + 3][n]);
                *(ushort4*)&Bt[(size_t)(n0 + n) * KDIM + k0 + k] = o;
            }
        }
    } else {
        int i = (blockIdx.x - NMB) * 256 + t;
        float4 v = x[i];
        ushort4 o;
        o.x = f2bf(v.x); o.y = f2bf(v.y); o.z = f2bf(v.z); o.w = f2bf(v.w);
        xb[i] = o;
    }
}

// ---------------- GEMM: C[m][n] = sum_k A[m][k]*Bt[n][k] + bias[n] ----------------
// Round-0 proven structure (98.6us) + structured-zero K-skip:
//   mask p=0 blocks make Bt exactly 0 on: cls0 (n<512): k in [1024,1536)u[2560,3072);
//   cls2 (n>=1024): k in [0,512)u[1536,2048). Skip-class tiles run two 96-aligned
//   ranges of 11 steps (22 vs 32 steps, -31% work).
// Slot-balanced dispatch: the 256 full-K tiles (bx 4..7) take bik 0..255 -> one per
// CU first-slot; 512 skip tiles fill slots 2-3. Per-CU work 32+22+22=76 step-units
// vs 96 homogeneous. XCD by-band (by = xcd*8 + l) identical to round 0.
__device__ __forceinline__ void gload_lds16(const void* g, void* l) {
    __builtin_amdgcn_global_load_lds(
        (const __attribute__((address_space(1))) unsigned int*)g,
        (__attribute__((address_space(3))) unsigned int*)l, 16, 0, 0);
}

#define PLANE 4096   // u16 per k-plane (128 rows * 32)

__global__ void __launch_bounds__(256, 3)
gemm_kernel(const u16* __restrict__ A,   // [M][K] bf16
            const u16* __restrict__ B,   // [N][K] bf16
            const float* __restrict__ bias,
            float* __restrict__ C) {     // [M][N] fp32
    __shared__ u16 sA[3 * PLANE];  // 24 KiB
    __shared__ u16 sB[3 * PLANE];  // 24 KiB

    const int tid  = threadIdx.x;
    const int wave = tid >> 6;
    const int lane = tid & 63;

    // Balanced remap: bik<256 -> full-K tiles (bx 4..7); else skip tiles (bx 0..3,8..11).
    // Both groups keep XCD r -> by in [8r, 8r+8) for L2 banding.
    const int bik = blockIdx.x;
    int bx, by;
    if (bik < 256) {
        const int xcd = bik & 7, j = bik >> 3;   // j 0..31
        by = xcd * 8 + (j & 7);
        bx = 4 + (j >> 3);                        // 4..7
    } else {
        const int i = bik - 256, xcd = i & 7, j = i >> 3;  // j 0..63
        by = xcd * 8 + (j & 7);
        const int b = j >> 3;                     // 0..7
        bx = b < 4 ? b : b + 4;                   // 0..3, 8..11
    }
    const int m0 = by * BM, n0 = bx * BN;

    // k-range table by n-class (all bounds 96-aligned; supersets of nonzero support)
    const int cls  = bx >> 2;  // 0,1,2
    const int klo0 = cls == 0 ? 0    : (cls == 1 ? 0    : 480);
    const int khi0 = cls == 0 ? 1056 : (cls == 1 ? 3072 : 1536);
    const int klo1 = cls == 0 ? 1536 : (cls == 1 ? 3072 : 2016);
    const int khi1 = cls == 0 ? 2592 : (cls == 1 ? 3072 : 3072);

    const int srow = lane >> 2;
    const int scol = ((lane & 3) ^ ((lane >> 3) & 3)) * 8;

    const int wm = (wave >> 1) * 64;
    const int wn = (wave & 1) * 64;
    const int fr = lane & 15;
    const int fq = lane >> 4;
    const int fsw = (fq ^ ((fr >> 1) & 3)) * 8;

    f32x4 acc[4][4] = {};

    const u16* gA0 = A + (size_t)(m0 + wave * 16 + srow) * KDIM + scol;
    const u16* gB0 = B + (size_t)(n0 + wave * 16 + srow) * KDIM + scol;
    u16* lA0 = &sA[(wave * 16) * 32];
    u16* lA1 = &sA[(wave * 16 + 64) * 32];
    u16* lB0 = &sB[(wave * 16) * 32];
    u16* lB1 = &sB[(wave * 16 + 64) * 32];

#pragma unroll
    for (int seg = 0; seg < 2; ++seg) {
        const int klo = seg ? klo1 : klo0;
        const int khi = seg ? khi1 : khi0;
        for (int k0 = klo; k0 < khi; k0 += BK) {
            __syncthreads();
#pragma unroll
            for (int p = 0; p < 3; ++p) {
                gload_lds16(gA0 + k0 + p * 32,                      lA0 + p * PLANE);
                gload_lds16(gA0 + k0 + p * 32 + (size_t)64 * KDIM,  lA1 + p * PLANE);
                gload_lds16(gB0 + k0 + p * 32,                      lB0 + p * PLANE);
                gload_lds16(gB0 + k0 + p * 32 + (size_t)64 * KDIM,  lB1 + p * PLANE);
            }
            __syncthreads();

#pragma unroll
            for (int h = 0; h < 3; ++h) {
                const u16* pA = &sA[h * PLANE];
                const u16* pB = &sB[h * PLANE];
                bf16x8 af[4], bfv[4];
#pragma unroll
                for (int mt = 0; mt < 4; ++mt)
                    af[mt] = *(const bf16x8*)&pA[(wm + mt * 16 + fr) * 32 + fsw];
#pragma unroll
                for (int nt = 0; nt < 4; ++nt)
                    bfv[nt] = *(const bf16x8*)&pB[(wn + nt * 16 + fr) * 32 + fsw];
#pragma unroll
                for (int mt = 0; mt < 4; ++mt)
#pragma unroll
                    for (int nt = 0; nt < 4; ++nt)
                        acc[mt][nt] = __builtin_amdgcn_mfma_f32_16x16x32_bf16(
                            af[mt], bfv[nt], acc[mt][nt], 0, 0, 0);
            }
        }
    }

    // epilogue: C/D layout col = lane&15, row = (lane>>4)*4 + reg  [m89-verified]
#pragma unroll
    for (int nt = 0; nt < 4; ++nt) {
        int n = n0 + wn + nt * 16 + fr;
        float bv = bias[n];
#pragma unroll
        for (int mt = 0; mt < 4; ++mt) {
            int m = m0 + wm + mt * 16 + fq * 4;
#pragma unroll
            for (int r = 0; r < 4; ++r)
                C[(size_t)(m + r) * NDIM + n] = acc[mt][nt][r] + bv;
        }
    }
}

extern "C" void kernel_launch(void* const* d_in, const int* in_sizes, int n_in,
                              void* d_out, int out_size, void* d_ws, size_t ws_size,
                              hipStream_t stream) {
    const float* x    = (const float*)d_in[0];   // [8192][3072]
    const float* w    = (const float*)d_in[1];   // [3072][1536]
    const float* bias = (const float*)d_in[2];   // [1536]
    const float* mask = (const float*)d_in[3];   // [1536][3072]
    float* out = (float*)d_out;                  // [8192][1536]

    u16* xb = (u16*)d_ws;                                   // 50331648 B
    u16* Bt = (u16*)((char*)d_ws + (size_t)50331648);       //  9437184 B

    prep_kernel<<<NMB + NCVT, 256, 0, stream>>>(w, mask, Bt, (const float4*)x, (ushort4*)xb);
    gemm_kernel<<<(MDIM / BM) * (NDIM / BN), 256, 0, stream>>>(xb, Bt, bias, out);
}